// Round 11
// baseline (168.541 us; speedup 1.0000x reference)
//
#include <hip/hip_runtime.h>

#define N_NODES 50000
#define NB 782          // buckets of 64 dst nodes: ceil(50000/64)
#define PA_CH 8192      // edges per chunk in hist/scatter
#define CAP 2048        // max edges per bucket (avg 1023; uniform-random tail safe)

typedef __attribute__((ext_vector_type(8))) short bf16x8;
typedef __attribute__((ext_vector_type(4))) float f32x4;

// bf16 helpers (RNE pack, shift unpack)
static __device__ __forceinline__ unsigned short f2bf(float f) {
    unsigned int u = __float_as_uint(f);
    u += 0x7fffu + ((u >> 16) & 1u);
    return (unsigned short)(u >> 16);
}
static __device__ __forceinline__ float bfl(unsigned int u) { return __uint_as_float(u << 16); }
static __device__ __forceinline__ float bfh(unsigned int u) { return __uint_as_float(u & 0xffff0000u); }

// ================= CSR build: deterministic, no global atomics =================

// pass 0: per-chunk histogram -> cnt2d[blk][NB]
__global__ __launch_bounds__(256) void chunk_hist(const int* __restrict__ dst,
                                                  int* __restrict__ cnt2d, int E) {
    __shared__ int bins[NB];
    int b = blockIdx.x;
    int base = b * PA_CH;
    int end = base + PA_CH; if (end > E) end = E;
    for (int i = threadIdx.x; i < NB; i += 256) bins[i] = 0;
    __syncthreads();
    for (int i = base + threadIdx.x; i < end; i += 256)
        atomicAdd(&bins[dst[i] >> 6], 1);
    __syncthreads();
    for (int i = threadIdx.x; i < NB; i += 256) cnt2d[b * NB + i] = bins[i];
}

// pass 1 (one block): per-(blk,bucket) exclusive offsets + bucket base scan.
// off2d[b][k] = bptr[k] + sum_{b'<b} cnt2d[b'][k];  bptr = excl-scan of col sums.
__global__ __launch_bounds__(1024) void scan2d(int* __restrict__ cnt2d,   // in: counts, out: off2d
                                               int* __restrict__ bptr,
                                               int* __restrict__ row_ptr,
                                               int nblk, int E) {
    int tid = threadIdx.x;
    int run = 0;
    if (tid < NB) {
        for (int b = 0; b < nblk; ++b) {
            int t = cnt2d[b * NB + tid];
            cnt2d[b * NB + tid] = run;   // pre-base exclusive partial
            run += t;
        }
    }
    // wave-scan of column totals (run) over NB entries
    int v = (tid < NB) ? run : 0;
    int lane = tid & 63, wv = tid >> 6;
    int incl = v;
    for (int off = 1; off < 64; off <<= 1) {
        int t = __shfl_up(incl, off);
        if (lane >= off) incl += t;
    }
    __shared__ int ws[16];
    if (lane == 63) ws[wv] = incl;
    __syncthreads();
    int woff = 0;
    for (int i = 0; i < wv; ++i) woff += ws[i];
    int excl = woff + incl - v;
    if (tid < NB) {
        bptr[tid] = excl;
        for (int b = 0; b < nblk; ++b) cnt2d[b * NB + tid] += excl;
    }
    if (tid == NB - 1) { bptr[NB] = excl + v; row_ptr[N_NODES] = E; }
}

// pass 2: scatter packed (src | dst_low6<<16) using precomputed per-chunk offsets.
// Only intra-block LDS atomics (arrival order canonicalized by bucket_sort).
__global__ __launch_bounds__(256) void bucket_scatter(const int* __restrict__ src,
                                                      const int* __restrict__ dst,
                                                      const int* __restrict__ off2d,
                                                      unsigned* __restrict__ ebuf, int E) {
    __shared__ int cur[NB];
    int b = blockIdx.x;
    int base = b * PA_CH;
    int end = base + PA_CH; if (end > E) end = E;
    for (int i = threadIdx.x; i < NB; i += 256) cur[i] = off2d[b * NB + i];
    __syncthreads();
    for (int i = base + threadIdx.x; i < end; i += 256) {
        int d = dst[i];
        int k = d >> 6;
        int pos = atomicAdd(&cur[k], 1);
        ebuf[pos] = (unsigned)src[i] | ((unsigned)(d & 63) << 16);
    }
}

// pass 3: per-bucket LDS counting scatter by dst_low (arrival-ordered), then a
// PARALLEL RANK-SORT within each dst segment -> bit-deterministic sorted
// (dst,src) edge list + row_ptr.
__global__ __launch_bounds__(256) void bucket_sort(const unsigned* __restrict__ ebuf,
                                                   const int* __restrict__ bptr,
                                                   unsigned short* __restrict__ edge_src,
                                                   int* __restrict__ row_ptr) {
    int b = blockIdx.x;
    int start = bptr[b], bend = bptr[b + 1];
    int n = bend - start; if (n > CAP) n = CAP;
    __shared__ unsigned raw[CAP];
    __shared__ unsigned grp[CAP];     // segment-grouped full keys (seg<<16 | src)
    __shared__ int bins[64], pref[64], cur[64];
    int tid = threadIdx.x;
    for (int i = tid; i < n; i += 256) raw[i] = ebuf[start + i];
    if (tid < 64) bins[tid] = 0;
    __syncthreads();
    for (int i = tid; i < n; i += 256) atomicAdd(&bins[raw[i] >> 16], 1);
    __syncthreads();
    if (tid < 64) {
        int v = bins[tid];
        int incl = v;
        for (int off = 1; off < 64; off <<= 1) {
            int t = __shfl_up(incl, off);
            if (tid >= off) incl += t;
        }
        pref[tid] = incl - v;
        cur[tid] = incl - v;
    }
    __syncthreads();
    for (int i = tid; i < n; i += 256) {
        unsigned r = raw[i];
        int pos = atomicAdd(&cur[r >> 16], 1);
        grp[pos] = r;
    }
    __syncthreads();
    // parallel rank-sort: independent loads, no serial chain
    for (int i = tid; i < n; i += 256) {
        unsigned v = grp[i];
        int s = v >> 16;
        int lo = pref[s];
        int len = bins[s];
        int rank = 0;
        for (int j = lo; j < lo + len; ++j) {
            unsigned u = grp[j];
            rank += (u < v) || (u == v && j < i);
        }
        edge_src[start + lo + rank] = (unsigned short)(v & 0xffffu);
    }
    int d0 = b * 64;
    if (tid < 64 && d0 + tid < N_NODES) row_ptr[d0 + tid] = start + pref[tid];
}

// ================= weight prep =================

__global__ void prep_all(const float* __restrict__ W0, const float* __restrict__ W1,
                         const float* __restrict__ W2, short* __restrict__ Wb) {
    int i = blockIdx.x * 256 + threadIdx.x;
    if (i >= 19 * 2048) return;
    const float* W; int fout; int local;
    if (i < 8 * 2048)       { W = W0; fout = 128; local = i; }
    else if (i < 16 * 2048) { W = W1; fout = 128; local = i - 8 * 2048; }
    else                    { W = W2; fout = 40;  local = i - 16 * 2048; }
    int j = local & 7;
    int l = (local >> 3) & 63;
    int kt = (local >> 9) & 3;
    int ct = local >> 11;
    int col = ct * 16 + (l & 15);
    int k = kt * 32 + (l >> 4) * 8 + j;
    float v = (col < fout) ? W[col * 128 + k] : 0.0f;
    Wb[i] = (short)f2bf(v);
}

// ================= standalone MFMA GEMM (layer 0: x f32 -> h0 bf16) =================

template <int FT>
__global__ __launch_bounds__(256) void gemm_mfma(const float* __restrict__ inp,
                                                 const short* __restrict__ Wb,
                                                 unsigned short* __restrict__ out, int fout) {
    const int l = threadIdx.x & 63;
    const int w = threadIdx.x >> 6;
    const int r16 = l & 15;
    const int khalf = l >> 4;
    int rowA = blockIdx.x * 64 + w * 16 + r16;
    if (rowA >= N_NODES) rowA = N_NODES - 1;  // garbage stays in unstored rows

    f32x4 acc[FT];
#pragma unroll
    for (int ct = 0; ct < FT; ++ct) acc[ct] = (f32x4){0.f, 0.f, 0.f, 0.f};

#pragma unroll
    for (int kt = 0; kt < 4; ++kt) {
        const float* ip = inp + (size_t)rowA * 128 + kt * 32 + khalf * 8;
        float4 f0 = ((const float4*)ip)[0];
        float4 f1 = ((const float4*)ip)[1];
        bf16x8 a;
        a[0] = (short)f2bf(f0.x); a[1] = (short)f2bf(f0.y);
        a[2] = (short)f2bf(f0.z); a[3] = (short)f2bf(f0.w);
        a[4] = (short)f2bf(f1.x); a[5] = (short)f2bf(f1.y);
        a[6] = (short)f2bf(f1.z); a[7] = (short)f2bf(f1.w);
#pragma unroll
        for (int ct = 0; ct < FT; ++ct) {
            bf16x8 bfr = *(const bf16x8*)(Wb + (((ct * 4 + kt) * 64 + l) * 8));
            acc[ct] = __builtin_amdgcn_mfma_f32_16x16x32_bf16(a, bfr, acc[ct], 0, 0, 0);
        }
    }

    const int rowD0 = blockIdx.x * 64 + w * 16 + khalf * 4;
#pragma unroll
    for (int ct = 0; ct < FT; ++ct) {
        int col = ct * 16 + r16;
#pragma unroll
        for (int rr = 0; rr < 4; ++rr) {
            int row = rowD0 + rr;
            if (row < N_NODES && col < fout)
                out[(size_t)row * fout + col] = f2bf(acc[ct][rr]);
        }
    }
}

// ================= fused gather + GEMM (layers 1,2) =================
template <int NCT>
__global__ __launch_bounds__(256) void gather_gemm(const unsigned short* __restrict__ h,
                                                   const int* __restrict__ row_ptr,
                                                   const unsigned short* __restrict__ es,
                                                   const float* __restrict__ bias,
                                                   const short* __restrict__ Wb,
                                                   unsigned short* __restrict__ out, int fout) {
    __shared__ float agg[16][132];
    const int node0 = blockIdx.x * 16;

    {   // ---- gather phase: 16 threads per node, 8 feats each ----
        const int nl = threadIdx.x >> 4;
        const int q  = threadIdx.x & 15;
        const int node = node0 + nl;
        int beg = row_ptr[node], end = row_ptr[node + 1];
        float acc[8];
        float4 c0 = ((const float4*)bias)[q * 2];
        float4 c1 = ((const float4*)bias)[q * 2 + 1];
        acc[0] = c0.x; acc[1] = c0.y; acc[2] = c0.z; acc[3] = c0.w;
        acc[4] = c1.x; acc[5] = c1.y; acc[6] = c1.z; acc[7] = c1.w;
        int e = beg;
        for (; e + 1 < end; e += 2) {
            int s0 = es[e], s1 = es[e + 1];
            const uint4 v0 = ((const uint4*)(h + (size_t)s0 * 128))[q];
            const uint4 v1 = ((const uint4*)(h + (size_t)s1 * 128))[q];
            acc[0] += bfl(v0.x); acc[1] += bfh(v0.x);
            acc[2] += bfl(v0.y); acc[3] += bfh(v0.y);
            acc[4] += bfl(v0.z); acc[5] += bfh(v0.z);
            acc[6] += bfl(v0.w); acc[7] += bfh(v0.w);
            acc[0] += bfl(v1.x); acc[1] += bfh(v1.x);
            acc[2] += bfl(v1.y); acc[3] += bfh(v1.y);
            acc[4] += bfl(v1.z); acc[5] += bfh(v1.z);
            acc[6] += bfl(v1.w); acc[7] += bfh(v1.w);
        }
        if (e < end) {
            int s = es[e];
            const uint4 v = ((const uint4*)(h + (size_t)s * 128))[q];
            acc[0] += bfl(v.x); acc[1] += bfh(v.x);
            acc[2] += bfl(v.y); acc[3] += bfh(v.y);
            acc[4] += bfl(v.z); acc[5] += bfh(v.z);
            acc[6] += bfl(v.w); acc[7] += bfh(v.w);
        }
        float* row = &agg[nl][q * 8];
        ((float4*)row)[0] = make_float4(fmaxf(acc[0], 0.f), fmaxf(acc[1], 0.f),
                                        fmaxf(acc[2], 0.f), fmaxf(acc[3], 0.f));
        ((float4*)row)[1] = make_float4(fmaxf(acc[4], 0.f), fmaxf(acc[5], 0.f),
                                        fmaxf(acc[6], 0.f), fmaxf(acc[7], 0.f));
    }
    __syncthreads();

    // ---- MFMA phase ----
    const int l = threadIdx.x & 63;
    const int w = threadIdx.x >> 6;
    const int r16 = l & 15;
    const int khalf = l >> 4;
    f32x4 acc[(NCT + 3) / 4];
#pragma unroll
    for (int i = 0; i < (NCT + 3) / 4; ++i) acc[i] = (f32x4){0.f, 0.f, 0.f, 0.f};

#pragma unroll
    for (int kt = 0; kt < 4; ++kt) {
        const float* ap = &agg[r16][kt * 32 + khalf * 8];
        float4 f0 = ((const float4*)ap)[0];
        float4 f1 = ((const float4*)ap)[1];
        bf16x8 a;
        a[0] = (short)f2bf(f0.x); a[1] = (short)f2bf(f0.y);
        a[2] = (short)f2bf(f0.z); a[3] = (short)f2bf(f0.w);
        a[4] = (short)f2bf(f1.x); a[5] = (short)f2bf(f1.y);
        a[6] = (short)f2bf(f1.z); a[7] = (short)f2bf(f1.w);
        int i = 0;
#pragma unroll
        for (int ct = w; ct < NCT; ct += 4, ++i) {
            bf16x8 bfr = *(const bf16x8*)(Wb + (((ct * 4 + kt) * 64 + l) * 8));
            acc[i] = __builtin_amdgcn_mfma_f32_16x16x32_bf16(a, bfr, acc[i], 0, 0, 0);
        }
    }

    {
        int i = 0;
#pragma unroll
        for (int ct = w; ct < NCT; ct += 4, ++i) {
            int col = ct * 16 + r16;
            if (col < fout) {
#pragma unroll
                for (int rr = 0; rr < 4; ++rr)
                    out[(size_t)(node0 + khalf * 4 + rr) * fout + col] = f2bf(acc[i][rr]);
            }
        }
    }
}

// ================= final gather (F=40, bf16 in -> f32 out + bias) =================

__global__ void gather_f40_bf(const unsigned short* __restrict__ h,
                              const int* __restrict__ row_ptr,
                              const unsigned short* __restrict__ es,
                              const float* __restrict__ b,
                              float* __restrict__ out) {
    int gid = blockIdx.x * blockDim.x + threadIdx.x;
    int node = gid / 5;
    int q = gid - node * 5;
    if (node >= N_NODES) return;
    int beg = row_ptr[node];
    int end = row_ptr[node + 1];
    float acc[8];
#pragma unroll
    for (int j = 0; j < 8; ++j) acc[j] = b[q * 8 + j];
    int e = beg;
    for (; e + 1 < end; e += 2) {
        int s0 = es[e], s1 = es[e + 1];
        const uint4 v0 = *(const uint4*)(h + (size_t)s0 * 40 + q * 8);
        const uint4 v1 = *(const uint4*)(h + (size_t)s1 * 40 + q * 8);
        acc[0] += bfl(v0.x); acc[1] += bfh(v0.x);
        acc[2] += bfl(v0.y); acc[3] += bfh(v0.y);
        acc[4] += bfl(v0.z); acc[5] += bfh(v0.z);
        acc[6] += bfl(v0.w); acc[7] += bfh(v0.w);
        acc[0] += bfl(v1.x); acc[1] += bfh(v1.x);
        acc[2] += bfl(v1.y); acc[3] += bfh(v1.y);
        acc[4] += bfl(v1.z); acc[5] += bfh(v1.z);
        acc[6] += bfl(v1.w); acc[7] += bfh(v1.w);
    }
    if (e < end) {
        int s = es[e];
        const uint4 v = *(const uint4*)(h + (size_t)s * 40 + q * 8);
        acc[0] += bfl(v.x); acc[1] += bfh(v.x);
        acc[2] += bfl(v.y); acc[3] += bfh(v.y);
        acc[4] += bfl(v.z); acc[5] += bfh(v.z);
        acc[6] += bfl(v.w); acc[7] += bfh(v.w);
    }
    float* o = out + (size_t)node * 40 + q * 8;
    ((float4*)o)[0] = make_float4(acc[0], acc[1], acc[2], acc[3]);
    ((float4*)o)[1] = make_float4(acc[4], acc[5], acc[6], acc[7]);
}

// ================= host =================

extern "C" void kernel_launch(void* const* d_in, const int* in_sizes, int n_in,
                              void* d_out, int out_size, void* d_ws, size_t ws_size,
                              hipStream_t stream) {
    const float* x  = (const float*)d_in[0];
    const int*   ei = (const int*)d_in[1];
    const float* W0 = (const float*)d_in[2];
    const float* b0 = (const float*)d_in[3];
    const float* W1 = (const float*)d_in[4];
    const float* b1 = (const float*)d_in[5];
    const float* W2 = (const float*)d_in[6];
    const float* b2 = (const float*)d_in[7];
    float* out = (float*)d_out;

    const int E = in_sizes[1] / 2;
    const int* src = ei;
    const int* dst = ei + E;
    const int nblk = (E + PA_CH - 1) / PA_CH;

    // workspace layout
    char* p = (char*)d_ws;
    unsigned short* hb0 = (unsigned short*)p;  p += (size_t)N_NODES * 128 * 2;  // L0 out (bf16)
    unsigned short* hb1 = (unsigned short*)p;  p += (size_t)N_NODES * 128 * 2;  // F1 out (bf16)
    unsigned short* hb2 = (unsigned short*)p;  p += (size_t)N_NODES * 40 * 2;   // F2 out (bf16)
    short* wb = (short*)p;                     p += 19 * 2048 * 2;              // wb0|wb1|wb2
    unsigned* ebuf = (unsigned*)p;             p += (size_t)E * 4;
    int* row_ptr = (int*)p;                    p += (N_NODES + 1) * 4;
    int* bptr = (int*)p;                       p += (NB + 1) * 4;
    int* cnt2d = (int*)p;                      p += (size_t)nblk * NB * 4;      // counts -> offsets
    unsigned short* edge_src = (unsigned short*)p;  // E u16

    short* wb0 = wb;
    short* wb1 = wb + 8 * 2048;
    short* wb2 = wb + 16 * 2048;

    // ---- CSR build (deterministic; no global atomics in hist/scan/scatter) ----
    chunk_hist<<<nblk, 256, 0, stream>>>(dst, cnt2d, E);
    scan2d<<<1, 1024, 0, stream>>>(cnt2d, bptr, row_ptr, nblk, E);
    bucket_scatter<<<nblk, 256, 0, stream>>>(src, dst, cnt2d, ebuf, E);
    bucket_sort<<<NB, 256, 0, stream>>>(ebuf, bptr, edge_src, row_ptr);

    // ---- weight prep ----
    prep_all<<<(19 * 2048 + 255) / 256, 256, 0, stream>>>(W0, W1, W2, wb);

    // ---- layer 0: h0 = bf16(x @ W0^T) ----
    gemm_mfma<8><<<(N_NODES + 63) / 64, 256, 0, stream>>>(x, wb0, hb0, 128);

    // ---- layer 1 fused: h1 = bf16(relu(gather(h0)+b0) @ W1^T) ----
    gather_gemm<8><<<N_NODES / 16, 256, 0, stream>>>(hb0, row_ptr, edge_src, b0, wb1, hb1, 128);

    // ---- layer 2 fused: h2 = bf16(relu(gather(h1)+b1) @ W2^T) ----
    gather_gemm<3><<<N_NODES / 16, 256, 0, stream>>>(hb1, row_ptr, edge_src, b1, wb2, hb2, 40);

    // ---- final aggregation: out = gather(h2) + b2 ----
    gather_f40_bf<<<(N_NODES * 5 + 255) / 256, 256, 0, stream>>>(hb2, row_ptr, edge_src, b2, out);
}

// Round 12
// 134.135 us; speedup vs baseline: 1.2565x; 1.2565x over previous
//
#include <hip/hip_runtime.h>

#define N_NODES 50000
#define NB 782          // buckets of 64 dst nodes: ceil(50000/64)
#define PA_CH 4096      // edges per block in bucket_scatter
#define CAP 2048        // max edges per bucket (avg 1023; uniform-random tail safe)

typedef __attribute__((ext_vector_type(8))) short bf16x8;
typedef __attribute__((ext_vector_type(4))) float f32x4;

// bf16 helpers (RNE pack, shift unpack)
static __device__ __forceinline__ unsigned short f2bf(float f) {
    unsigned int u = __float_as_uint(f);
    u += 0x7fffu + ((u >> 16) & 1u);
    return (unsigned short)(u >> 16);
}
static __device__ __forceinline__ float bfl(unsigned int u) { return __uint_as_float(u << 16); }
static __device__ __forceinline__ float bfh(unsigned int u) { return __uint_as_float(u & 0xffff0000u); }

// ================= CSR build: 2-level bucket sort (deterministic) =================

__global__ void zero_gcnt(int* __restrict__ g) {
    int i = blockIdx.x * 256 + threadIdx.x;
    if (i < NB) g[i] = 0;
}

// grid-stride LDS histogram, int4-vectorized dst reads (E % 4 == 0)
__global__ __launch_bounds__(256) void bucket_hist(const int* __restrict__ dst,
                                                   int* __restrict__ gcnt, int E) {
    __shared__ int bins[NB];
    for (int i = threadIdx.x; i < NB; i += 256) bins[i] = 0;
    __syncthreads();
    const int E4 = E >> 2;
    for (int i = blockIdx.x * 256 + threadIdx.x; i < E4; i += gridDim.x * 256) {
        int4 d = ((const int4*)dst)[i];
        atomicAdd(&bins[d.x >> 6], 1);
        atomicAdd(&bins[d.y >> 6], 1);
        atomicAdd(&bins[d.z >> 6], 1);
        atomicAdd(&bins[d.w >> 6], 1);
    }
    __syncthreads();
    for (int i = threadIdx.x; i < NB; i += 256) {
        int c = bins[i];
        if (c) atomicAdd(&gcnt[i], c);
    }
}

__global__ __launch_bounds__(1024) void scan_nb(const int* __restrict__ gcnt,
                                                int* __restrict__ bptr, int* __restrict__ gcur,
                                                int* __restrict__ row_ptr, int E) {
    int tid = threadIdx.x;
    int v = (tid < NB) ? gcnt[tid] : 0;
    int lane = tid & 63, wv = tid >> 6;
    int incl = v;
    for (int off = 1; off < 64; off <<= 1) {
        int t = __shfl_up(incl, off);
        if (lane >= off) incl += t;
    }
    __shared__ int ws[16];
    if (lane == 63) ws[wv] = incl;
    __syncthreads();
    int woff = 0;
    for (int i = 0; i < wv; ++i) woff += ws[i];
    int excl = woff + incl - v;
    if (tid < NB) { bptr[tid] = excl; gcur[tid] = excl; }
    if (tid == NB - 1) { bptr[NB] = excl + v; row_ptr[N_NODES] = E; }
}

// pass A: scatter packed (src | dst_low6<<16) into bucket regions, block-reserved,
// int4-vectorized loads. Arrival order nondeterministic; canonicalized by pass B.
__global__ __launch_bounds__(256) void bucket_scatter(const int* __restrict__ src,
                                                      const int* __restrict__ dst,
                                                      int* __restrict__ gcur,
                                                      unsigned* __restrict__ ebuf, int E) {
    __shared__ int cnt[NB];
    __shared__ int run[NB];
    int base = blockIdx.x * PA_CH;
    int end = base + PA_CH; if (end > E) end = E;
    int b4 = base >> 2, e4 = end >> 2;     // PA_CH and E are multiples of 4
    for (int i = threadIdx.x; i < NB; i += 256) cnt[i] = 0;
    __syncthreads();
    for (int i = b4 + threadIdx.x; i < e4; i += 256) {
        int4 d = ((const int4*)dst)[i];
        atomicAdd(&cnt[d.x >> 6], 1);
        atomicAdd(&cnt[d.y >> 6], 1);
        atomicAdd(&cnt[d.z >> 6], 1);
        atomicAdd(&cnt[d.w >> 6], 1);
    }
    __syncthreads();
    for (int i = threadIdx.x; i < NB; i += 256) {
        int c = cnt[i];
        run[i] = c ? atomicAdd(&gcur[i], c) : 0;
    }
    __syncthreads();
    for (int i = b4 + threadIdx.x; i < e4; i += 256) {
        int4 d = ((const int4*)dst)[i];
        int4 s = ((const int4*)src)[i];
        int p0 = atomicAdd(&run[d.x >> 6], 1);
        ebuf[p0] = (unsigned)s.x | ((unsigned)(d.x & 63) << 16);
        int p1 = atomicAdd(&run[d.y >> 6], 1);
        ebuf[p1] = (unsigned)s.y | ((unsigned)(d.y & 63) << 16);
        int p2 = atomicAdd(&run[d.z >> 6], 1);
        ebuf[p2] = (unsigned)s.z | ((unsigned)(d.z & 63) << 16);
        int p3 = atomicAdd(&run[d.w >> 6], 1);
        ebuf[p3] = (unsigned)s.w | ((unsigned)(d.w & 63) << 16);
    }
}

// pass B: per-bucket LDS counting scatter by dst_low (arrival-ordered), then a
// PARALLEL RANK-SORT within each dst segment -> bit-deterministic sorted
// (dst,src) edge list + row_ptr.
__global__ __launch_bounds__(256) void bucket_sort(const unsigned* __restrict__ ebuf,
                                                   const int* __restrict__ bptr,
                                                   unsigned short* __restrict__ edge_src,
                                                   int* __restrict__ row_ptr) {
    int b = blockIdx.x;
    int start = bptr[b], bend = bptr[b + 1];
    int n = bend - start; if (n > CAP) n = CAP;
    __shared__ unsigned raw[CAP];
    __shared__ unsigned grp[CAP];     // segment-grouped full keys (seg<<16 | src)
    __shared__ int bins[64], pref[64], cur[64];
    int tid = threadIdx.x;
    for (int i = tid; i < n; i += 256) raw[i] = ebuf[start + i];
    if (tid < 64) bins[tid] = 0;
    __syncthreads();
    for (int i = tid; i < n; i += 256) atomicAdd(&bins[raw[i] >> 16], 1);
    __syncthreads();
    if (tid < 64) {
        int v = bins[tid];
        int incl = v;
        for (int off = 1; off < 64; off <<= 1) {
            int t = __shfl_up(incl, off);
            if (tid >= off) incl += t;
        }
        pref[tid] = incl - v;
        cur[tid] = incl - v;
    }
    __syncthreads();
    for (int i = tid; i < n; i += 256) {
        unsigned r = raw[i];
        int pos = atomicAdd(&cur[r >> 16], 1);
        grp[pos] = r;
    }
    __syncthreads();
    // parallel rank-sort: independent loads, no serial chain
    for (int i = tid; i < n; i += 256) {
        unsigned v = grp[i];
        int s = v >> 16;
        int lo = pref[s];
        int len = bins[s];
        int rank = 0;
        for (int j = lo; j < lo + len; ++j) {
            unsigned u = grp[j];
            rank += (u < v) || (u == v && j < i);
        }
        edge_src[start + lo + rank] = (unsigned short)(v & 0xffffu);
    }
    int d0 = b * 64;
    if (tid < 64 && d0 + tid < N_NODES) row_ptr[d0 + tid] = start + pref[tid];
}

// ================= weight prep =================

__global__ void prep_all(const float* __restrict__ W0, const float* __restrict__ W1,
                         const float* __restrict__ W2, short* __restrict__ Wb) {
    int i = blockIdx.x * 256 + threadIdx.x;
    if (i >= 19 * 2048) return;
    const float* W; int fout; int local;
    if (i < 8 * 2048)       { W = W0; fout = 128; local = i; }
    else if (i < 16 * 2048) { W = W1; fout = 128; local = i - 8 * 2048; }
    else                    { W = W2; fout = 40;  local = i - 16 * 2048; }
    int j = local & 7;
    int l = (local >> 3) & 63;
    int kt = (local >> 9) & 3;
    int ct = local >> 11;
    int col = ct * 16 + (l & 15);
    int k = kt * 32 + (l >> 4) * 8 + j;
    float v = (col < fout) ? W[col * 128 + k] : 0.0f;
    Wb[i] = (short)f2bf(v);
}

// ================= standalone MFMA GEMM (layer 0: x f32 -> h0 bf16) =================

template <int FT>
__global__ __launch_bounds__(256) void gemm_mfma(const float* __restrict__ inp,
                                                 const short* __restrict__ Wb,
                                                 unsigned short* __restrict__ out, int fout) {
    const int l = threadIdx.x & 63;
    const int w = threadIdx.x >> 6;
    const int r16 = l & 15;
    const int khalf = l >> 4;
    int rowA = blockIdx.x * 64 + w * 16 + r16;
    if (rowA >= N_NODES) rowA = N_NODES - 1;  // garbage stays in unstored rows

    f32x4 acc[FT];
#pragma unroll
    for (int ct = 0; ct < FT; ++ct) acc[ct] = (f32x4){0.f, 0.f, 0.f, 0.f};

#pragma unroll
    for (int kt = 0; kt < 4; ++kt) {
        const float* ip = inp + (size_t)rowA * 128 + kt * 32 + khalf * 8;
        float4 f0 = ((const float4*)ip)[0];
        float4 f1 = ((const float4*)ip)[1];
        bf16x8 a;
        a[0] = (short)f2bf(f0.x); a[1] = (short)f2bf(f0.y);
        a[2] = (short)f2bf(f0.z); a[3] = (short)f2bf(f0.w);
        a[4] = (short)f2bf(f1.x); a[5] = (short)f2bf(f1.y);
        a[6] = (short)f2bf(f1.z); a[7] = (short)f2bf(f1.w);
#pragma unroll
        for (int ct = 0; ct < FT; ++ct) {
            bf16x8 bfr = *(const bf16x8*)(Wb + (((ct * 4 + kt) * 64 + l) * 8));
            acc[ct] = __builtin_amdgcn_mfma_f32_16x16x32_bf16(a, bfr, acc[ct], 0, 0, 0);
        }
    }

    const int rowD0 = blockIdx.x * 64 + w * 16 + khalf * 4;
#pragma unroll
    for (int ct = 0; ct < FT; ++ct) {
        int col = ct * 16 + r16;
#pragma unroll
        for (int rr = 0; rr < 4; ++rr) {
            int row = rowD0 + rr;
            if (row < N_NODES && col < fout)
                out[(size_t)row * fout + col] = f2bf(acc[ct][rr]);
        }
    }
}

// ================= fused gather + GEMM (layers 1,2) =================
template <int NCT>
__global__ __launch_bounds__(256) void gather_gemm(const unsigned short* __restrict__ h,
                                                   const int* __restrict__ row_ptr,
                                                   const unsigned short* __restrict__ es,
                                                   const float* __restrict__ bias,
                                                   const short* __restrict__ Wb,
                                                   unsigned short* __restrict__ out, int fout) {
    __shared__ float agg[16][132];
    const int node0 = blockIdx.x * 16;

    {   // ---- gather phase: 16 threads per node, 8 feats each ----
        const int nl = threadIdx.x >> 4;
        const int q  = threadIdx.x & 15;
        const int node = node0 + nl;
        int beg = row_ptr[node], end = row_ptr[node + 1];
        float acc[8];
        float4 c0 = ((const float4*)bias)[q * 2];
        float4 c1 = ((const float4*)bias)[q * 2 + 1];
        acc[0] = c0.x; acc[1] = c0.y; acc[2] = c0.z; acc[3] = c0.w;
        acc[4] = c1.x; acc[5] = c1.y; acc[6] = c1.z; acc[7] = c1.w;
        int e = beg;
        for (; e + 1 < end; e += 2) {
            int s0 = es[e], s1 = es[e + 1];
            const uint4 v0 = ((const uint4*)(h + (size_t)s0 * 128))[q];
            const uint4 v1 = ((const uint4*)(h + (size_t)s1 * 128))[q];
            acc[0] += bfl(v0.x); acc[1] += bfh(v0.x);
            acc[2] += bfl(v0.y); acc[3] += bfh(v0.y);
            acc[4] += bfl(v0.z); acc[5] += bfh(v0.z);
            acc[6] += bfl(v0.w); acc[7] += bfh(v0.w);
            acc[0] += bfl(v1.x); acc[1] += bfh(v1.x);
            acc[2] += bfl(v1.y); acc[3] += bfh(v1.y);
            acc[4] += bfl(v1.z); acc[5] += bfh(v1.z);
            acc[6] += bfl(v1.w); acc[7] += bfh(v1.w);
        }
        if (e < end) {
            int s = es[e];
            const uint4 v = ((const uint4*)(h + (size_t)s * 128))[q];
            acc[0] += bfl(v.x); acc[1] += bfh(v.x);
            acc[2] += bfl(v.y); acc[3] += bfh(v.y);
            acc[4] += bfl(v.z); acc[5] += bfh(v.z);
            acc[6] += bfl(v.w); acc[7] += bfh(v.w);
        }
        float* row = &agg[nl][q * 8];
        ((float4*)row)[0] = make_float4(fmaxf(acc[0], 0.f), fmaxf(acc[1], 0.f),
                                        fmaxf(acc[2], 0.f), fmaxf(acc[3], 0.f));
        ((float4*)row)[1] = make_float4(fmaxf(acc[4], 0.f), fmaxf(acc[5], 0.f),
                                        fmaxf(acc[6], 0.f), fmaxf(acc[7], 0.f));
    }
    __syncthreads();

    // ---- MFMA phase ----
    const int l = threadIdx.x & 63;
    const int w = threadIdx.x >> 6;
    const int r16 = l & 15;
    const int khalf = l >> 4;
    f32x4 acc[(NCT + 3) / 4];
#pragma unroll
    for (int i = 0; i < (NCT + 3) / 4; ++i) acc[i] = (f32x4){0.f, 0.f, 0.f, 0.f};

#pragma unroll
    for (int kt = 0; kt < 4; ++kt) {
        const float* ap = &agg[r16][kt * 32 + khalf * 8];
        float4 f0 = ((const float4*)ap)[0];
        float4 f1 = ((const float4*)ap)[1];
        bf16x8 a;
        a[0] = (short)f2bf(f0.x); a[1] = (short)f2bf(f0.y);
        a[2] = (short)f2bf(f0.z); a[3] = (short)f2bf(f0.w);
        a[4] = (short)f2bf(f1.x); a[5] = (short)f2bf(f1.y);
        a[6] = (short)f2bf(f1.z); a[7] = (short)f2bf(f1.w);
        int i = 0;
#pragma unroll
        for (int ct = w; ct < NCT; ct += 4, ++i) {
            bf16x8 bfr = *(const bf16x8*)(Wb + (((ct * 4 + kt) * 64 + l) * 8));
            acc[i] = __builtin_amdgcn_mfma_f32_16x16x32_bf16(a, bfr, acc[i], 0, 0, 0);
        }
    }

    {
        int i = 0;
#pragma unroll
        for (int ct = w; ct < NCT; ct += 4, ++i) {
            int col = ct * 16 + r16;
            if (col < fout) {
#pragma unroll
                for (int rr = 0; rr < 4; ++rr)
                    out[(size_t)(node0 + khalf * 4 + rr) * fout + col] = f2bf(acc[i][rr]);
            }
        }
    }
}

// ================= final gather (F=40, bf16 in -> f32 out + bias) =================

__global__ void gather_f40_bf(const unsigned short* __restrict__ h,
                              const int* __restrict__ row_ptr,
                              const unsigned short* __restrict__ es,
                              const float* __restrict__ b,
                              float* __restrict__ out) {
    int gid = blockIdx.x * blockDim.x + threadIdx.x;
    int node = gid / 5;
    int q = gid - node * 5;
    if (node >= N_NODES) return;
    int beg = row_ptr[node];
    int end = row_ptr[node + 1];
    float acc[8];
#pragma unroll
    for (int j = 0; j < 8; ++j) acc[j] = b[q * 8 + j];
    int e = beg;
    for (; e + 1 < end; e += 2) {
        int s0 = es[e], s1 = es[e + 1];
        const uint4 v0 = *(const uint4*)(h + (size_t)s0 * 40 + q * 8);
        const uint4 v1 = *(const uint4*)(h + (size_t)s1 * 40 + q * 8);
        acc[0] += bfl(v0.x); acc[1] += bfh(v0.x);
        acc[2] += bfl(v0.y); acc[3] += bfh(v0.y);
        acc[4] += bfl(v0.z); acc[5] += bfh(v0.z);
        acc[6] += bfl(v0.w); acc[7] += bfh(v0.w);
        acc[0] += bfl(v1.x); acc[1] += bfh(v1.x);
        acc[2] += bfl(v1.y); acc[3] += bfh(v1.y);
        acc[4] += bfl(v1.z); acc[5] += bfh(v1.z);
        acc[6] += bfl(v1.w); acc[7] += bfh(v1.w);
    }
    if (e < end) {
        int s = es[e];
        const uint4 v = *(const uint4*)(h + (size_t)s * 40 + q * 8);
        acc[0] += bfl(v.x); acc[1] += bfh(v.x);
        acc[2] += bfl(v.y); acc[3] += bfh(v.y);
        acc[4] += bfl(v.z); acc[5] += bfh(v.z);
        acc[6] += bfl(v.w); acc[7] += bfh(v.w);
    }
    float* o = out + (size_t)node * 40 + q * 8;
    ((float4*)o)[0] = make_float4(acc[0], acc[1], acc[2], acc[3]);
    ((float4*)o)[1] = make_float4(acc[4], acc[5], acc[6], acc[7]);
}

// ================= host =================

extern "C" void kernel_launch(void* const* d_in, const int* in_sizes, int n_in,
                              void* d_out, int out_size, void* d_ws, size_t ws_size,
                              hipStream_t stream) {
    const float* x  = (const float*)d_in[0];
    const int*   ei = (const int*)d_in[1];
    const float* W0 = (const float*)d_in[2];
    const float* b0 = (const float*)d_in[3];
    const float* W1 = (const float*)d_in[4];
    const float* b1 = (const float*)d_in[5];
    const float* W2 = (const float*)d_in[6];
    const float* b2 = (const float*)d_in[7];
    float* out = (float*)d_out;

    const int E = in_sizes[1] / 2;
    const int* src = ei;
    const int* dst = ei + E;

    // workspace layout
    char* p = (char*)d_ws;
    unsigned short* hb0 = (unsigned short*)p;  p += (size_t)N_NODES * 128 * 2;  // L0 out (bf16)
    unsigned short* hb1 = (unsigned short*)p;  p += (size_t)N_NODES * 128 * 2;  // F1 out (bf16)
    unsigned short* hb2 = (unsigned short*)p;  p += (size_t)N_NODES * 40 * 2;   // F2 out (bf16)
    short* wb = (short*)p;                     p += 19 * 2048 * 2;              // wb0|wb1|wb2
    unsigned* ebuf = (unsigned*)p;             p += (size_t)E * 4;
    int* row_ptr = (int*)p;                    p += (N_NODES + 1) * 4;
    int* bptr = (int*)p;                       p += (NB + 1) * 4;
    int* gcnt = (int*)p;                       p += NB * 4;
    int* gcur = (int*)p;                       p += NB * 4;
    unsigned short* edge_src = (unsigned short*)p;  // E u16

    short* wb0 = wb;
    short* wb1 = wb + 8 * 2048;
    short* wb2 = wb + 16 * 2048;

    // ---- CSR build (round-10 structure; int4-vectorized loads) ----
    zero_gcnt<<<4, 256, 0, stream>>>(gcnt);
    bucket_hist<<<256, 256, 0, stream>>>(dst, gcnt, E);
    scan_nb<<<1, 1024, 0, stream>>>(gcnt, bptr, gcur, row_ptr, E);
    bucket_scatter<<<(E + PA_CH - 1) / PA_CH, 256, 0, stream>>>(src, dst, gcur, ebuf, E);
    bucket_sort<<<NB, 256, 0, stream>>>(ebuf, bptr, edge_src, row_ptr);

    // ---- weight prep ----
    prep_all<<<(19 * 2048 + 255) / 256, 256, 0, stream>>>(W0, W1, W2, wb);

    // ---- layer 0: h0 = bf16(x @ W0^T) ----
    gemm_mfma<8><<<(N_NODES + 63) / 64, 256, 0, stream>>>(x, wb0, hb0, 128);

    // ---- layer 1 fused: h1 = bf16(relu(gather(h0)+b0) @ W1^T) ----
    gather_gemm<8><<<N_NODES / 16, 256, 0, stream>>>(hb0, row_ptr, edge_src, b0, wb1, hb1, 128);

    // ---- layer 2 fused: h2 = bf16(relu(gather(h1)+b1) @ W2^T) ----
    gather_gemm<3><<<N_NODES / 16, 256, 0, stream>>>(hb1, row_ptr, edge_src, b1, wb2, hb2, 40);

    // ---- final aggregation: out = gather(h2) + b2 ----
    gather_f40_bf<<<(N_NODES * 5 + 255) / 256, 256, 0, stream>>>(hb2, row_ptr, edge_src, b2, out);
}

// Round 13
// 124.800 us; speedup vs baseline: 1.3505x; 1.0748x over previous
//
#include <hip/hip_runtime.h>

#define N_NODES 50000
#define NB 782          // buckets of 64 dst nodes: ceil(50000/64)
#define PA_CH 4096      // edges per block in bucket_scatter
#define CAP 2048        // slots per bucket (avg fill 1023, sigma~32; overflow ~32 sigma)

typedef __attribute__((ext_vector_type(8))) short bf16x8;
typedef __attribute__((ext_vector_type(4))) float f32x4;

// bf16 helpers (RNE pack, shift unpack)
static __device__ __forceinline__ unsigned short f2bf(float f) {
    unsigned int u = __float_as_uint(f);
    u += 0x7fffu + ((u >> 16) & 1u);
    return (unsigned short)(u >> 16);
}
static __device__ __forceinline__ float bfl(unsigned int u) { return __uint_as_float(u << 16); }
static __device__ __forceinline__ float bfh(unsigned int u) { return __uint_as_float(u & 0xffff0000u); }

// ================= CSR build: slotted bucket scatter (no histogram pass) =================

__global__ void zero_gcnt(int* __restrict__ g) {
    int i = blockIdx.x * 256 + threadIdx.x;
    if (i < NB) g[i] = 0;
}

// Scatter packed (src | dst_low6<<16) into fixed-capacity bucket slots at b*CAP.
// LDS pre-count -> one global reservation per (block,bucket) -> slot writes.
// gcnt ends up holding the final per-bucket counts (consumed by scan_nb).
__global__ __launch_bounds__(256) void bucket_scatter(const int* __restrict__ src,
                                                      const int* __restrict__ dst,
                                                      int* __restrict__ gcnt,
                                                      unsigned* __restrict__ ebuf, int E) {
    __shared__ int cnt[NB];
    __shared__ int run[NB];
    int base = blockIdx.x * PA_CH;
    int end = base + PA_CH; if (end > E) end = E;
    int b4 = base >> 2, e4 = end >> 2;     // PA_CH and E are multiples of 4
    for (int i = threadIdx.x; i < NB; i += 256) cnt[i] = 0;
    __syncthreads();
    for (int i = b4 + threadIdx.x; i < e4; i += 256) {
        int4 d = ((const int4*)dst)[i];
        atomicAdd(&cnt[d.x >> 6], 1);
        atomicAdd(&cnt[d.y >> 6], 1);
        atomicAdd(&cnt[d.z >> 6], 1);
        atomicAdd(&cnt[d.w >> 6], 1);
    }
    __syncthreads();
    for (int i = threadIdx.x; i < NB; i += 256) {
        int c = cnt[i];
        run[i] = c ? (i * CAP + atomicAdd(&gcnt[i], c)) : 0;
    }
    __syncthreads();
    for (int i = b4 + threadIdx.x; i < e4; i += 256) {
        int4 d = ((const int4*)dst)[i];
        int4 s = ((const int4*)src)[i];
        int p0 = atomicAdd(&run[d.x >> 6], 1);
        ebuf[p0] = (unsigned)s.x | ((unsigned)(d.x & 63) << 16);
        int p1 = atomicAdd(&run[d.y >> 6], 1);
        ebuf[p1] = (unsigned)s.y | ((unsigned)(d.y & 63) << 16);
        int p2 = atomicAdd(&run[d.z >> 6], 1);
        ebuf[p2] = (unsigned)s.z | ((unsigned)(d.z & 63) << 16);
        int p3 = atomicAdd(&run[d.w >> 6], 1);
        ebuf[p3] = (unsigned)s.w | ((unsigned)(d.w & 63) << 16);
    }
}

// exclusive scan of final bucket counts -> bptr
__global__ __launch_bounds__(1024) void scan_nb(const int* __restrict__ gcnt,
                                                int* __restrict__ bptr,
                                                int* __restrict__ row_ptr, int E) {
    int tid = threadIdx.x;
    int v = (tid < NB) ? gcnt[tid] : 0;
    int lane = tid & 63, wv = tid >> 6;
    int incl = v;
    for (int off = 1; off < 64; off <<= 1) {
        int t = __shfl_up(incl, off);
        if (lane >= off) incl += t;
    }
    __shared__ int ws[16];
    if (lane == 63) ws[wv] = incl;
    __syncthreads();
    int woff = 0;
    for (int i = 0; i < wv; ++i) woff += ws[i];
    int excl = woff + incl - v;
    if (tid < NB) bptr[tid] = excl;
    if (tid == NB - 1) { bptr[NB] = excl + v; row_ptr[N_NODES] = E; }
}

// per-bucket: read slots, LDS counting scatter by dst_low, parallel rank-sort per
// dst segment, write compacted sorted edge list + row_ptr (bit-deterministic).
__global__ __launch_bounds__(256) void bucket_sort(const unsigned* __restrict__ ebuf,
                                                   const int* __restrict__ gcnt,
                                                   const int* __restrict__ bptr,
                                                   unsigned short* __restrict__ edge_src,
                                                   int* __restrict__ row_ptr) {
    int b = blockIdx.x;
    int start = bptr[b];
    int n = gcnt[b]; if (n > CAP) n = CAP;
    const unsigned* slot = ebuf + (size_t)b * CAP;
    __shared__ unsigned raw[CAP];
    __shared__ unsigned grp[CAP];     // segment-grouped full keys (seg<<16 | src)
    __shared__ int bins[64], pref[64], cur[64];
    int tid = threadIdx.x;
    for (int i = tid; i < n; i += 256) raw[i] = slot[i];
    if (tid < 64) bins[tid] = 0;
    __syncthreads();
    for (int i = tid; i < n; i += 256) atomicAdd(&bins[raw[i] >> 16], 1);
    __syncthreads();
    if (tid < 64) {
        int v = bins[tid];
        int incl = v;
        for (int off = 1; off < 64; off <<= 1) {
            int t = __shfl_up(incl, off);
            if (tid >= off) incl += t;
        }
        pref[tid] = incl - v;
        cur[tid] = incl - v;
    }
    __syncthreads();
    for (int i = tid; i < n; i += 256) {
        unsigned r = raw[i];
        int pos = atomicAdd(&cur[r >> 16], 1);
        grp[pos] = r;
    }
    __syncthreads();
    // parallel rank-sort: independent loads, no serial chain
    for (int i = tid; i < n; i += 256) {
        unsigned v = grp[i];
        int s = v >> 16;
        int lo = pref[s];
        int len = bins[s];
        int rank = 0;
        for (int j = lo; j < lo + len; ++j) {
            unsigned u = grp[j];
            rank += (u < v) || (u == v && j < i);
        }
        edge_src[start + lo + rank] = (unsigned short)(v & 0xffffu);
    }
    int d0 = b * 64;
    if (tid < 64 && d0 + tid < N_NODES) row_ptr[d0 + tid] = start + pref[tid];
}

// ================= weight prep =================

__global__ void prep_all(const float* __restrict__ W0, const float* __restrict__ W1,
                         const float* __restrict__ W2, short* __restrict__ Wb) {
    int i = blockIdx.x * 256 + threadIdx.x;
    if (i >= 19 * 2048) return;
    const float* W; int fout; int local;
    if (i < 8 * 2048)       { W = W0; fout = 128; local = i; }
    else if (i < 16 * 2048) { W = W1; fout = 128; local = i - 8 * 2048; }
    else                    { W = W2; fout = 40;  local = i - 16 * 2048; }
    int j = local & 7;
    int l = (local >> 3) & 63;
    int kt = (local >> 9) & 3;
    int ct = local >> 11;
    int col = ct * 16 + (l & 15);
    int k = kt * 32 + (l >> 4) * 8 + j;
    float v = (col < fout) ? W[col * 128 + k] : 0.0f;
    Wb[i] = (short)f2bf(v);
}

// ================= standalone MFMA GEMM (layer 0: x f32 -> h0 bf16) =================

template <int FT>
__global__ __launch_bounds__(256) void gemm_mfma(const float* __restrict__ inp,
                                                 const short* __restrict__ Wb,
                                                 unsigned short* __restrict__ out, int fout) {
    const int l = threadIdx.x & 63;
    const int w = threadIdx.x >> 6;
    const int r16 = l & 15;
    const int khalf = l >> 4;
    int rowA = blockIdx.x * 64 + w * 16 + r16;
    if (rowA >= N_NODES) rowA = N_NODES - 1;  // garbage stays in unstored rows

    f32x4 acc[FT];
#pragma unroll
    for (int ct = 0; ct < FT; ++ct) acc[ct] = (f32x4){0.f, 0.f, 0.f, 0.f};

#pragma unroll
    for (int kt = 0; kt < 4; ++kt) {
        const float* ip = inp + (size_t)rowA * 128 + kt * 32 + khalf * 8;
        float4 f0 = ((const float4*)ip)[0];
        float4 f1 = ((const float4*)ip)[1];
        bf16x8 a;
        a[0] = (short)f2bf(f0.x); a[1] = (short)f2bf(f0.y);
        a[2] = (short)f2bf(f0.z); a[3] = (short)f2bf(f0.w);
        a[4] = (short)f2bf(f1.x); a[5] = (short)f2bf(f1.y);
        a[6] = (short)f2bf(f1.z); a[7] = (short)f2bf(f1.w);
#pragma unroll
        for (int ct = 0; ct < FT; ++ct) {
            bf16x8 bfr = *(const bf16x8*)(Wb + (((ct * 4 + kt) * 64 + l) * 8));
            acc[ct] = __builtin_amdgcn_mfma_f32_16x16x32_bf16(a, bfr, acc[ct], 0, 0, 0);
        }
    }

    const int rowD0 = blockIdx.x * 64 + w * 16 + khalf * 4;
#pragma unroll
    for (int ct = 0; ct < FT; ++ct) {
        int col = ct * 16 + r16;
#pragma unroll
        for (int rr = 0; rr < 4; ++rr) {
            int row = rowD0 + rr;
            if (row < N_NODES && col < fout)
                out[(size_t)row * fout + col] = f2bf(acc[ct][rr]);
        }
    }
}

// ================= fused gather + GEMM (layers 1,2) =================
template <int NCT>
__global__ __launch_bounds__(256) void gather_gemm(const unsigned short* __restrict__ h,
                                                   const int* __restrict__ row_ptr,
                                                   const unsigned short* __restrict__ es,
                                                   const float* __restrict__ bias,
                                                   const short* __restrict__ Wb,
                                                   unsigned short* __restrict__ out, int fout) {
    __shared__ float agg[16][132];
    const int node0 = blockIdx.x * 16;

    {   // ---- gather phase: 16 threads per node, 8 feats each ----
        const int nl = threadIdx.x >> 4;
        const int q  = threadIdx.x & 15;
        const int node = node0 + nl;
        int beg = row_ptr[node], end = row_ptr[node + 1];
        float acc[8];
        float4 c0 = ((const float4*)bias)[q * 2];
        float4 c1 = ((const float4*)bias)[q * 2 + 1];
        acc[0] = c0.x; acc[1] = c0.y; acc[2] = c0.z; acc[3] = c0.w;
        acc[4] = c1.x; acc[5] = c1.y; acc[6] = c1.z; acc[7] = c1.w;
        int e = beg;
        for (; e + 1 < end; e += 2) {
            int s0 = es[e], s1 = es[e + 1];
            const uint4 v0 = ((const uint4*)(h + (size_t)s0 * 128))[q];
            const uint4 v1 = ((const uint4*)(h + (size_t)s1 * 128))[q];
            acc[0] += bfl(v0.x); acc[1] += bfh(v0.x);
            acc[2] += bfl(v0.y); acc[3] += bfh(v0.y);
            acc[4] += bfl(v0.z); acc[5] += bfh(v0.z);
            acc[6] += bfl(v0.w); acc[7] += bfh(v0.w);
            acc[0] += bfl(v1.x); acc[1] += bfh(v1.x);
            acc[2] += bfl(v1.y); acc[3] += bfh(v1.y);
            acc[4] += bfl(v1.z); acc[5] += bfh(v1.z);
            acc[6] += bfl(v1.w); acc[7] += bfh(v1.w);
        }
        if (e < end) {
            int s = es[e];
            const uint4 v = ((const uint4*)(h + (size_t)s * 128))[q];
            acc[0] += bfl(v.x); acc[1] += bfh(v.x);
            acc[2] += bfl(v.y); acc[3] += bfh(v.y);
            acc[4] += bfl(v.z); acc[5] += bfh(v.z);
            acc[6] += bfl(v.w); acc[7] += bfh(v.w);
        }
        float* row = &agg[nl][q * 8];
        ((float4*)row)[0] = make_float4(fmaxf(acc[0], 0.f), fmaxf(acc[1], 0.f),
                                        fmaxf(acc[2], 0.f), fmaxf(acc[3], 0.f));
        ((float4*)row)[1] = make_float4(fmaxf(acc[4], 0.f), fmaxf(acc[5], 0.f),
                                        fmaxf(acc[6], 0.f), fmaxf(acc[7], 0.f));
    }
    __syncthreads();

    // ---- MFMA phase ----
    const int l = threadIdx.x & 63;
    const int w = threadIdx.x >> 6;
    const int r16 = l & 15;
    const int khalf = l >> 4;
    f32x4 acc[(NCT + 3) / 4];
#pragma unroll
    for (int i = 0; i < (NCT + 3) / 4; ++i) acc[i] = (f32x4){0.f, 0.f, 0.f, 0.f};

#pragma unroll
    for (int kt = 0; kt < 4; ++kt) {
        const float* ap = &agg[r16][kt * 32 + khalf * 8];
        float4 f0 = ((const float4*)ap)[0];
        float4 f1 = ((const float4*)ap)[1];
        bf16x8 a;
        a[0] = (short)f2bf(f0.x); a[1] = (short)f2bf(f0.y);
        a[2] = (short)f2bf(f0.z); a[3] = (short)f2bf(f0.w);
        a[4] = (short)f2bf(f1.x); a[5] = (short)f2bf(f1.y);
        a[6] = (short)f2bf(f1.z); a[7] = (short)f2bf(f1.w);
        int i = 0;
#pragma unroll
        for (int ct = w; ct < NCT; ct += 4, ++i) {
            bf16x8 bfr = *(const bf16x8*)(Wb + (((ct * 4 + kt) * 64 + l) * 8));
            acc[i] = __builtin_amdgcn_mfma_f32_16x16x32_bf16(a, bfr, acc[i], 0, 0, 0);
        }
    }

    {
        int i = 0;
#pragma unroll
        for (int ct = w; ct < NCT; ct += 4, ++i) {
            int col = ct * 16 + r16;
            if (col < fout) {
#pragma unroll
                for (int rr = 0; rr < 4; ++rr)
                    out[(size_t)(node0 + khalf * 4 + rr) * fout + col] = f2bf(acc[i][rr]);
            }
        }
    }
}

// ================= final gather (F=40, bf16 in -> f32 out + bias) =================

__global__ void gather_f40_bf(const unsigned short* __restrict__ h,
                              const int* __restrict__ row_ptr,
                              const unsigned short* __restrict__ es,
                              const float* __restrict__ b,
                              float* __restrict__ out) {
    int gid = blockIdx.x * blockDim.x + threadIdx.x;
    int node = gid / 5;
    int q = gid - node * 5;
    if (node >= N_NODES) return;
    int beg = row_ptr[node];
    int end = row_ptr[node + 1];
    float acc[8];
#pragma unroll
    for (int j = 0; j < 8; ++j) acc[j] = b[q * 8 + j];
    int e = beg;
    for (; e + 1 < end; e += 2) {
        int s0 = es[e], s1 = es[e + 1];
        const uint4 v0 = *(const uint4*)(h + (size_t)s0 * 40 + q * 8);
        const uint4 v1 = *(const uint4*)(h + (size_t)s1 * 40 + q * 8);
        acc[0] += bfl(v0.x); acc[1] += bfh(v0.x);
        acc[2] += bfl(v0.y); acc[3] += bfh(v0.y);
        acc[4] += bfl(v0.z); acc[5] += bfh(v0.z);
        acc[6] += bfl(v0.w); acc[7] += bfh(v0.w);
        acc[0] += bfl(v1.x); acc[1] += bfh(v1.x);
        acc[2] += bfl(v1.y); acc[3] += bfh(v1.y);
        acc[4] += bfl(v1.z); acc[5] += bfh(v1.z);
        acc[6] += bfl(v1.w); acc[7] += bfh(v1.w);
    }
    if (e < end) {
        int s = es[e];
        const uint4 v = *(const uint4*)(h + (size_t)s * 40 + q * 8);
        acc[0] += bfl(v.x); acc[1] += bfh(v.x);
        acc[2] += bfl(v.y); acc[3] += bfh(v.y);
        acc[4] += bfl(v.z); acc[5] += bfh(v.z);
        acc[6] += bfl(v.w); acc[7] += bfh(v.w);
    }
    float* o = out + (size_t)node * 40 + q * 8;
    ((float4*)o)[0] = make_float4(acc[0], acc[1], acc[2], acc[3]);
    ((float4*)o)[1] = make_float4(acc[4], acc[5], acc[6], acc[7]);
}

// ================= host =================

extern "C" void kernel_launch(void* const* d_in, const int* in_sizes, int n_in,
                              void* d_out, int out_size, void* d_ws, size_t ws_size,
                              hipStream_t stream) {
    const float* x  = (const float*)d_in[0];
    const int*   ei = (const int*)d_in[1];
    const float* W0 = (const float*)d_in[2];
    const float* b0 = (const float*)d_in[3];
    const float* W1 = (const float*)d_in[4];
    const float* b1 = (const float*)d_in[5];
    const float* W2 = (const float*)d_in[6];
    const float* b2 = (const float*)d_in[7];
    float* out = (float*)d_out;

    const int E = in_sizes[1] / 2;
    const int* src = ei;
    const int* dst = ei + E;

    // workspace layout
    char* p = (char*)d_ws;
    unsigned short* hb0 = (unsigned short*)p;  p += (size_t)N_NODES * 128 * 2;  // L0 out (bf16)
    unsigned short* hb1 = (unsigned short*)p;  p += (size_t)N_NODES * 128 * 2;  // F1 out (bf16)
    unsigned short* hb2 = (unsigned short*)p;  p += (size_t)N_NODES * 40 * 2;   // F2 out (bf16)
    short* wb = (short*)p;                     p += 19 * 2048 * 2;              // wb0|wb1|wb2
    unsigned* ebuf = (unsigned*)p;             p += (size_t)NB * CAP * 4;       // slotted buckets
    int* row_ptr = (int*)p;                    p += (N_NODES + 1) * 4;
    int* bptr = (int*)p;                       p += (NB + 1) * 4;
    int* gcnt = (int*)p;                       p += NB * 4;
    unsigned short* edge_src = (unsigned short*)p;  // E u16

    short* wb0 = wb;
    short* wb1 = wb + 8 * 2048;
    short* wb2 = wb + 16 * 2048;

    // ---- CSR build (slotted scatter; no histogram pass) ----
    zero_gcnt<<<4, 256, 0, stream>>>(gcnt);
    bucket_scatter<<<(E + PA_CH - 1) / PA_CH, 256, 0, stream>>>(src, dst, gcnt, ebuf, E);
    scan_nb<<<1, 1024, 0, stream>>>(gcnt, bptr, row_ptr, E);
    bucket_sort<<<NB, 256, 0, stream>>>(ebuf, gcnt, bptr, edge_src, row_ptr);

    // ---- weight prep ----
    prep_all<<<(19 * 2048 + 255) / 256, 256, 0, stream>>>(W0, W1, W2, wb);

    // ---- layer 0: h0 = bf16(x @ W0^T) ----
    gemm_mfma<8><<<(N_NODES + 63) / 64, 256, 0, stream>>>(x, wb0, hb0, 128);

    // ---- layer 1 fused: h1 = bf16(relu(gather(h0)+b0) @ W1^T) ----
    gather_gemm<8><<<N_NODES / 16, 256, 0, stream>>>(hb0, row_ptr, edge_src, b0, wb1, hb1, 128);

    // ---- layer 2 fused: h2 = bf16(relu(gather(h1)+b1) @ W2^T) ----
    gather_gemm<3><<<N_NODES / 16, 256, 0, stream>>>(hb1, row_ptr, edge_src, b1, wb2, hb2, 40);

    // ---- final aggregation: out = gather(h2) + b2 ----
    gather_f40_bf<<<(N_NODES * 5 + 255) / 256, 256, 0, stream>>>(hb2, row_ptr, edge_src, b2, out);
}

// Round 14
// 116.882 us; speedup vs baseline: 1.4420x; 1.0677x over previous
//
#include <hip/hip_runtime.h>

#define N_NODES 50000
#define NB 782          // buckets of 64 dst nodes: ceil(50000/64)
#define PA_CH 4096      // edges per scatter block
#define CAP 2048        // slots per bucket (avg fill 1023, sigma~32; overflow ~32 sigma)

typedef __attribute__((ext_vector_type(8))) short bf16x8;
typedef __attribute__((ext_vector_type(4))) float f32x4;

// bf16 helpers (RNE pack, shift unpack)
static __device__ __forceinline__ unsigned short f2bf(float f) {
    unsigned int u = __float_as_uint(f);
    u += 0x7fffu + ((u >> 16) & 1u);
    return (unsigned short)(u >> 16);
}
static __device__ __forceinline__ float bfl(unsigned int u) { return __uint_as_float(u << 16); }
static __device__ __forceinline__ float bfh(unsigned int u) { return __uint_as_float(u & 0xffff0000u); }

// ================= zero gcnt + weight prep (one tiny kernel) =================

__global__ void zero_prep(int* __restrict__ g,
                          const float* __restrict__ W0, const float* __restrict__ W1,
                          const float* __restrict__ W2, short* __restrict__ Wb) {
    int i = blockIdx.x * 256 + threadIdx.x;
    if (i < NB) g[i] = 0;
    if (i >= 19 * 2048) return;
    const float* W; int fout; int local;
    if (i < 8 * 2048)       { W = W0; fout = 128; local = i; }
    else if (i < 16 * 2048) { W = W1; fout = 128; local = i - 8 * 2048; }
    else                    { W = W2; fout = 40;  local = i - 16 * 2048; }
    int j = local & 7;
    int l = (local >> 3) & 63;
    int kt = (local >> 9) & 3;
    int ct = local >> 11;
    int col = ct * 16 + (l & 15);
    int k = kt * 32 + (l >> 4) * 8 + j;
    float v = (col < fout) ? W[col * 128 + k] : 0.0f;
    Wb[i] = (short)f2bf(v);
}

// ================= fused phase 1: bucket scatter (blocks [0,SB)) =================
// ================= + layer-0 MFMA GEMM (blocks [SB, SB+GB)) =================
// Disjoint data; scatter is slotted (no histogram pass), gcnt ends with final counts.

__global__ __launch_bounds__(256) void fused_phase1(const int* __restrict__ src,
                                                    const int* __restrict__ dst,
                                                    int* __restrict__ gcnt,
                                                    unsigned* __restrict__ ebuf, int E, int SB,
                                                    const float* __restrict__ x,
                                                    const short* __restrict__ wb0,
                                                    unsigned short* __restrict__ hb0) {
    __shared__ int cnt[NB];
    __shared__ int run[NB];
    if (blockIdx.x < (unsigned)SB) {
        // ---- bucket scatter: packed (src | dst_low6<<16) into slots at b*CAP ----
        int base = blockIdx.x * PA_CH;
        int end = base + PA_CH; if (end > E) end = E;
        int b4 = base >> 2, e4 = end >> 2;     // PA_CH and E are multiples of 4
        for (int i = threadIdx.x; i < NB; i += 256) cnt[i] = 0;
        __syncthreads();
        for (int i = b4 + threadIdx.x; i < e4; i += 256) {
            int4 d = ((const int4*)dst)[i];
            atomicAdd(&cnt[d.x >> 6], 1);
            atomicAdd(&cnt[d.y >> 6], 1);
            atomicAdd(&cnt[d.z >> 6], 1);
            atomicAdd(&cnt[d.w >> 6], 1);
        }
        __syncthreads();
        for (int i = threadIdx.x; i < NB; i += 256) {
            int c = cnt[i];
            run[i] = c ? (i * CAP + atomicAdd(&gcnt[i], c)) : 0;
        }
        __syncthreads();
        for (int i = b4 + threadIdx.x; i < e4; i += 256) {
            int4 d = ((const int4*)dst)[i];
            int4 s = ((const int4*)src)[i];
            int p0 = atomicAdd(&run[d.x >> 6], 1);
            ebuf[p0] = (unsigned)s.x | ((unsigned)(d.x & 63) << 16);
            int p1 = atomicAdd(&run[d.y >> 6], 1);
            ebuf[p1] = (unsigned)s.y | ((unsigned)(d.y & 63) << 16);
            int p2 = atomicAdd(&run[d.z >> 6], 1);
            ebuf[p2] = (unsigned)s.z | ((unsigned)(d.z & 63) << 16);
            int p3 = atomicAdd(&run[d.w >> 6], 1);
            ebuf[p3] = (unsigned)s.w | ((unsigned)(d.w & 63) << 16);
        }
    } else {
        // ---- layer-0 GEMM: hb0 = bf16(x @ W0^T), 64 rows per block ----
        const int bid = blockIdx.x - SB;
        const int l = threadIdx.x & 63;
        const int w = threadIdx.x >> 6;
        const int r16 = l & 15;
        const int khalf = l >> 4;
        int rowA = bid * 64 + w * 16 + r16;
        if (rowA >= N_NODES) rowA = N_NODES - 1;

        f32x4 acc[8];
#pragma unroll
        for (int ct = 0; ct < 8; ++ct) acc[ct] = (f32x4){0.f, 0.f, 0.f, 0.f};

#pragma unroll
        for (int kt = 0; kt < 4; ++kt) {
            const float* ip = x + (size_t)rowA * 128 + kt * 32 + khalf * 8;
            float4 f0 = ((const float4*)ip)[0];
            float4 f1 = ((const float4*)ip)[1];
            bf16x8 a;
            a[0] = (short)f2bf(f0.x); a[1] = (short)f2bf(f0.y);
            a[2] = (short)f2bf(f0.z); a[3] = (short)f2bf(f0.w);
            a[4] = (short)f2bf(f1.x); a[5] = (short)f2bf(f1.y);
            a[6] = (short)f2bf(f1.z); a[7] = (short)f2bf(f1.w);
#pragma unroll
            for (int ct = 0; ct < 8; ++ct) {
                bf16x8 bfr = *(const bf16x8*)(wb0 + (((ct * 4 + kt) * 64 + l) * 8));
                acc[ct] = __builtin_amdgcn_mfma_f32_16x16x32_bf16(a, bfr, acc[ct], 0, 0, 0);
            }
        }

        const int rowD0 = bid * 64 + w * 16 + khalf * 4;
#pragma unroll
        for (int ct = 0; ct < 8; ++ct) {
            int col = ct * 16 + r16;
#pragma unroll
            for (int rr = 0; rr < 4; ++rr) {
                int row = rowD0 + rr;
                if (row < N_NODES)
                    hb0[(size_t)row * 128 + col] = f2bf(acc[ct][rr]);
            }
        }
    }
}

// ================= scan of final bucket counts -> bptr =================

__global__ __launch_bounds__(1024) void scan_nb(const int* __restrict__ gcnt,
                                                int* __restrict__ bptr,
                                                int* __restrict__ row_ptr, int E) {
    int tid = threadIdx.x;
    int v = (tid < NB) ? gcnt[tid] : 0;
    int lane = tid & 63, wv = tid >> 6;
    int incl = v;
    for (int off = 1; off < 64; off <<= 1) {
        int t = __shfl_up(incl, off);
        if (lane >= off) incl += t;
    }
    __shared__ int ws[16];
    if (lane == 63) ws[wv] = incl;
    __syncthreads();
    int woff = 0;
    for (int i = 0; i < wv; ++i) woff += ws[i];
    int excl = woff + incl - v;
    if (tid < NB) bptr[tid] = excl;
    if (tid == NB - 1) { bptr[NB] = excl + v; row_ptr[N_NODES] = E; }
}

// per-bucket: read slots, LDS counting scatter by dst_low, parallel rank-sort per
// dst segment, write compacted sorted edge list + row_ptr (bit-deterministic).
__global__ __launch_bounds__(256) void bucket_sort(const unsigned* __restrict__ ebuf,
                                                   const int* __restrict__ gcnt,
                                                   const int* __restrict__ bptr,
                                                   unsigned short* __restrict__ edge_src,
                                                   int* __restrict__ row_ptr) {
    int b = blockIdx.x;
    int start = bptr[b];
    int n = gcnt[b]; if (n > CAP) n = CAP;
    const unsigned* slot = ebuf + (size_t)b * CAP;
    __shared__ unsigned raw[CAP];
    __shared__ unsigned grp[CAP];     // segment-grouped full keys (seg<<16 | src)
    __shared__ int bins[64], pref[64], cur[64];
    int tid = threadIdx.x;
    for (int i = tid; i < n; i += 256) raw[i] = slot[i];
    if (tid < 64) bins[tid] = 0;
    __syncthreads();
    for (int i = tid; i < n; i += 256) atomicAdd(&bins[raw[i] >> 16], 1);
    __syncthreads();
    if (tid < 64) {
        int v = bins[tid];
        int incl = v;
        for (int off = 1; off < 64; off <<= 1) {
            int t = __shfl_up(incl, off);
            if (tid >= off) incl += t;
        }
        pref[tid] = incl - v;
        cur[tid] = incl - v;
    }
    __syncthreads();
    for (int i = tid; i < n; i += 256) {
        unsigned r = raw[i];
        int pos = atomicAdd(&cur[r >> 16], 1);
        grp[pos] = r;
    }
    __syncthreads();
    // parallel rank-sort: independent loads, no serial chain
    for (int i = tid; i < n; i += 256) {
        unsigned v = grp[i];
        int s = v >> 16;
        int lo = pref[s];
        int len = bins[s];
        int rank = 0;
        for (int j = lo; j < lo + len; ++j) {
            unsigned u = grp[j];
            rank += (u < v) || (u == v && j < i);
        }
        edge_src[start + lo + rank] = (unsigned short)(v & 0xffffu);
    }
    int d0 = b * 64;
    if (tid < 64 && d0 + tid < N_NODES) row_ptr[d0 + tid] = start + pref[tid];
}

// ================= fused gather + GEMM (layers 1,2) =================
template <int NCT>
__global__ __launch_bounds__(256) void gather_gemm(const unsigned short* __restrict__ h,
                                                   const int* __restrict__ row_ptr,
                                                   const unsigned short* __restrict__ es,
                                                   const float* __restrict__ bias,
                                                   const short* __restrict__ Wb,
                                                   unsigned short* __restrict__ out, int fout) {
    __shared__ float agg[16][132];
    const int node0 = blockIdx.x * 16;

    {   // ---- gather phase: 16 threads per node, 8 feats each ----
        const int nl = threadIdx.x >> 4;
        const int q  = threadIdx.x & 15;
        const int node = node0 + nl;
        int beg = row_ptr[node], end = row_ptr[node + 1];
        float acc[8];
        float4 c0 = ((const float4*)bias)[q * 2];
        float4 c1 = ((const float4*)bias)[q * 2 + 1];
        acc[0] = c0.x; acc[1] = c0.y; acc[2] = c0.z; acc[3] = c0.w;
        acc[4] = c1.x; acc[5] = c1.y; acc[6] = c1.z; acc[7] = c1.w;
        int e = beg;
        for (; e + 1 < end; e += 2) {
            int s0 = es[e], s1 = es[e + 1];
            const uint4 v0 = ((const uint4*)(h + (size_t)s0 * 128))[q];
            const uint4 v1 = ((const uint4*)(h + (size_t)s1 * 128))[q];
            acc[0] += bfl(v0.x); acc[1] += bfh(v0.x);
            acc[2] += bfl(v0.y); acc[3] += bfh(v0.y);
            acc[4] += bfl(v0.z); acc[5] += bfh(v0.z);
            acc[6] += bfl(v0.w); acc[7] += bfh(v0.w);
            acc[0] += bfl(v1.x); acc[1] += bfh(v1.x);
            acc[2] += bfl(v1.y); acc[3] += bfh(v1.y);
            acc[4] += bfl(v1.z); acc[5] += bfh(v1.z);
            acc[6] += bfl(v1.w); acc[7] += bfh(v1.w);
        }
        if (e < end) {
            int s = es[e];
            const uint4 v = ((const uint4*)(h + (size_t)s * 128))[q];
            acc[0] += bfl(v.x); acc[1] += bfh(v.x);
            acc[2] += bfl(v.y); acc[3] += bfh(v.y);
            acc[4] += bfl(v.z); acc[5] += bfh(v.z);
            acc[6] += bfl(v.w); acc[7] += bfh(v.w);
        }
        float* row = &agg[nl][q * 8];
        ((float4*)row)[0] = make_float4(fmaxf(acc[0], 0.f), fmaxf(acc[1], 0.f),
                                        fmaxf(acc[2], 0.f), fmaxf(acc[3], 0.f));
        ((float4*)row)[1] = make_float4(fmaxf(acc[4], 0.f), fmaxf(acc[5], 0.f),
                                        fmaxf(acc[6], 0.f), fmaxf(acc[7], 0.f));
    }
    __syncthreads();

    // ---- MFMA phase ----
    const int l = threadIdx.x & 63;
    const int w = threadIdx.x >> 6;
    const int r16 = l & 15;
    const int khalf = l >> 4;
    f32x4 acc[(NCT + 3) / 4];
#pragma unroll
    for (int i = 0; i < (NCT + 3) / 4; ++i) acc[i] = (f32x4){0.f, 0.f, 0.f, 0.f};

#pragma unroll
    for (int kt = 0; kt < 4; ++kt) {
        const float* ap = &agg[r16][kt * 32 + khalf * 8];
        float4 f0 = ((const float4*)ap)[0];
        float4 f1 = ((const float4*)ap)[1];
        bf16x8 a;
        a[0] = (short)f2bf(f0.x); a[1] = (short)f2bf(f0.y);
        a[2] = (short)f2bf(f0.z); a[3] = (short)f2bf(f0.w);
        a[4] = (short)f2bf(f1.x); a[5] = (short)f2bf(f1.y);
        a[6] = (short)f2bf(f1.z); a[7] = (short)f2bf(f1.w);
        int i = 0;
#pragma unroll
        for (int ct = w; ct < NCT; ct += 4, ++i) {
            bf16x8 bfr = *(const bf16x8*)(Wb + (((ct * 4 + kt) * 64 + l) * 8));
            acc[i] = __builtin_amdgcn_mfma_f32_16x16x32_bf16(a, bfr, acc[i], 0, 0, 0);
        }
    }

    {
        int i = 0;
#pragma unroll
        for (int ct = w; ct < NCT; ct += 4, ++i) {
            int col = ct * 16 + r16;
            if (col < fout) {
#pragma unroll
                for (int rr = 0; rr < 4; ++rr)
                    out[(size_t)(node0 + khalf * 4 + rr) * fout + col] = f2bf(acc[i][rr]);
            }
        }
    }
}

// ================= final gather (F=40, bf16 in -> f32 out + bias) =================

__global__ void gather_f40_bf(const unsigned short* __restrict__ h,
                              const int* __restrict__ row_ptr,
                              const unsigned short* __restrict__ es,
                              const float* __restrict__ b,
                              float* __restrict__ out) {
    int gid = blockIdx.x * blockDim.x + threadIdx.x;
    int node = gid / 5;
    int q = gid - node * 5;
    if (node >= N_NODES) return;
    int beg = row_ptr[node];
    int end = row_ptr[node + 1];
    float acc[8];
#pragma unroll
    for (int j = 0; j < 8; ++j) acc[j] = b[q * 8 + j];
    int e = beg;
    for (; e + 1 < end; e += 2) {
        int s0 = es[e], s1 = es[e + 1];
        const uint4 v0 = *(const uint4*)(h + (size_t)s0 * 40 + q * 8);
        const uint4 v1 = *(const uint4*)(h + (size_t)s1 * 40 + q * 8);
        acc[0] += bfl(v0.x); acc[1] += bfh(v0.x);
        acc[2] += bfl(v0.y); acc[3] += bfh(v0.y);
        acc[4] += bfl(v0.z); acc[5] += bfh(v0.z);
        acc[6] += bfl(v0.w); acc[7] += bfh(v0.w);
        acc[0] += bfl(v1.x); acc[1] += bfh(v1.x);
        acc[2] += bfl(v1.y); acc[3] += bfh(v1.y);
        acc[4] += bfl(v1.z); acc[5] += bfh(v1.z);
        acc[6] += bfl(v1.w); acc[7] += bfh(v1.w);
    }
    if (e < end) {
        int s = es[e];
        const uint4 v = *(const uint4*)(h + (size_t)s * 40 + q * 8);
        acc[0] += bfl(v.x); acc[1] += bfh(v.x);
        acc[2] += bfl(v.y); acc[3] += bfh(v.y);
        acc[4] += bfl(v.z); acc[5] += bfh(v.z);
        acc[6] += bfl(v.w); acc[7] += bfh(v.w);
    }
    float* o = out + (size_t)node * 40 + q * 8;
    ((float4*)o)[0] = make_float4(acc[0], acc[1], acc[2], acc[3]);
    ((float4*)o)[1] = make_float4(acc[4], acc[5], acc[6], acc[7]);
}

// ================= host =================

extern "C" void kernel_launch(void* const* d_in, const int* in_sizes, int n_in,
                              void* d_out, int out_size, void* d_ws, size_t ws_size,
                              hipStream_t stream) {
    const float* x  = (const float*)d_in[0];
    const int*   ei = (const int*)d_in[1];
    const float* W0 = (const float*)d_in[2];
    const float* b0 = (const float*)d_in[3];
    const float* W1 = (const float*)d_in[4];
    const float* b1 = (const float*)d_in[5];
    const float* W2 = (const float*)d_in[6];
    const float* b2 = (const float*)d_in[7];
    float* out = (float*)d_out;

    const int E = in_sizes[1] / 2;
    const int* src = ei;
    const int* dst = ei + E;

    // workspace layout
    char* p = (char*)d_ws;
    unsigned short* hb0 = (unsigned short*)p;  p += (size_t)N_NODES * 128 * 2;  // L0 out (bf16)
    unsigned short* hb1 = (unsigned short*)p;  p += (size_t)N_NODES * 128 * 2;  // F1 out (bf16)
    unsigned short* hb2 = (unsigned short*)p;  p += (size_t)N_NODES * 40 * 2;   // F2 out (bf16)
    short* wb = (short*)p;                     p += 19 * 2048 * 2;              // wb0|wb1|wb2
    unsigned* ebuf = (unsigned*)p;             p += (size_t)NB * CAP * 4;       // slotted buckets
    int* row_ptr = (int*)p;                    p += (N_NODES + 1) * 4;
    int* bptr = (int*)p;                       p += (NB + 1) * 4;
    int* gcnt = (int*)p;                       p += NB * 4;
    unsigned short* edge_src = (unsigned short*)p;  // E u16

    short* wb0 = wb;
    short* wb1 = wb + 8 * 2048;
    short* wb2 = wb + 16 * 2048;

    const int SB = (E + PA_CH - 1) / PA_CH;   // scatter blocks (196)
    const int GB = (N_NODES + 63) / 64;       // gemm blocks (782)

    // ---- phase 0: zero gcnt + prep all weights (one tiny kernel) ----
    zero_prep<<<(19 * 2048 + 255) / 256, 256, 0, stream>>>(gcnt, W0, W1, W2, wb);

    // ---- phase 1 (fused): bucket scatter  ||  layer-0 GEMM ----
    fused_phase1<<<SB + GB, 256, 0, stream>>>(src, dst, gcnt, ebuf, E, SB, x, wb0, hb0);

    // ---- CSR finalize ----
    scan_nb<<<1, 1024, 0, stream>>>(gcnt, bptr, row_ptr, E);
    bucket_sort<<<NB, 256, 0, stream>>>(ebuf, gcnt, bptr, edge_src, row_ptr);

    // ---- layer 1 fused: h1 = bf16(relu(gather(h0)+b0) @ W1^T) ----
    gather_gemm<8><<<N_NODES / 16, 256, 0, stream>>>(hb0, row_ptr, edge_src, b0, wb1, hb1, 128);

    // ---- layer 2 fused: h2 = bf16(relu(gather(h1)+b1) @ W2^T) ----
    gather_gemm<3><<<N_NODES / 16, 256, 0, stream>>>(hb1, row_ptr, edge_src, b1, wb2, hb2, 40);

    // ---- final aggregation: out = gather(h2) + b2 ----
    gather_f40_bf<<<(N_NODES * 5 + 255) / 256, 256, 0, stream>>>(hb2, row_ptr, edge_src, b2, out);
}

// Round 15
// 114.031 us; speedup vs baseline: 1.4780x; 1.0250x over previous
//
#include <hip/hip_runtime.h>

#define N_NODES 50000
#define NB 782          // buckets of 64 dst nodes: ceil(50000/64)
#define PA_CH 4096      // edges per scatter block
#define CAP 2048        // slots per bucket (avg fill 1023, sigma~32; overflow ~32 sigma)

typedef __attribute__((ext_vector_type(8))) short bf16x8;
typedef __attribute__((ext_vector_type(4))) float f32x4;

// bf16 helpers (RNE pack, shift unpack)
static __device__ __forceinline__ unsigned short f2bf(float f) {
    unsigned int u = __float_as_uint(f);
    u += 0x7fffu + ((u >> 16) & 1u);
    return (unsigned short)(u >> 16);
}
static __device__ __forceinline__ float bfl(unsigned int u) { return __uint_as_float(u << 16); }
static __device__ __forceinline__ float bfh(unsigned int u) { return __uint_as_float(u & 0xffff0000u); }

static __device__ __forceinline__ void acc8(float* acc, const uint4 v) {
    acc[0] += bfl(v.x); acc[1] += bfh(v.x);
    acc[2] += bfl(v.y); acc[3] += bfh(v.y);
    acc[4] += bfl(v.z); acc[5] += bfh(v.z);
    acc[6] += bfl(v.w); acc[7] += bfh(v.w);
}

// ================= zero gcnt + weight prep (one tiny kernel) =================

__global__ void zero_prep(int* __restrict__ g,
                          const float* __restrict__ W0, const float* __restrict__ W1,
                          const float* __restrict__ W2, short* __restrict__ Wb) {
    int i = blockIdx.x * 256 + threadIdx.x;
    if (i < NB) g[i] = 0;
    if (i >= 19 * 2048) return;
    const float* W; int fout; int local;
    if (i < 8 * 2048)       { W = W0; fout = 128; local = i; }
    else if (i < 16 * 2048) { W = W1; fout = 128; local = i - 8 * 2048; }
    else                    { W = W2; fout = 40;  local = i - 16 * 2048; }
    int j = local & 7;
    int l = (local >> 3) & 63;
    int kt = (local >> 9) & 3;
    int ct = local >> 11;
    int col = ct * 16 + (l & 15);
    int k = kt * 32 + (l >> 4) * 8 + j;
    float v = (col < fout) ? W[col * 128 + k] : 0.0f;
    Wb[i] = (short)f2bf(v);
}

// ================= fused phase 1: bucket scatter (blocks [0,SB)) =================
// ================= + layer-0 MFMA GEMM (blocks [SB, SB+GB)) =================

__global__ __launch_bounds__(256) void fused_phase1(const int* __restrict__ src,
                                                    const int* __restrict__ dst,
                                                    int* __restrict__ gcnt,
                                                    unsigned* __restrict__ ebuf, int E, int SB,
                                                    const float* __restrict__ x,
                                                    const short* __restrict__ wb0,
                                                    unsigned short* __restrict__ hb0) {
    __shared__ int cnt[NB];
    __shared__ int run[NB];
    if (blockIdx.x < (unsigned)SB) {
        // ---- bucket scatter: packed (src | dst_low6<<16) into slots at b*CAP ----
        int base = blockIdx.x * PA_CH;
        int end = base + PA_CH; if (end > E) end = E;
        int b4 = base >> 2, e4 = end >> 2;     // PA_CH and E are multiples of 4
        for (int i = threadIdx.x; i < NB; i += 256) cnt[i] = 0;
        __syncthreads();
        for (int i = b4 + threadIdx.x; i < e4; i += 256) {
            int4 d = ((const int4*)dst)[i];
            atomicAdd(&cnt[d.x >> 6], 1);
            atomicAdd(&cnt[d.y >> 6], 1);
            atomicAdd(&cnt[d.z >> 6], 1);
            atomicAdd(&cnt[d.w >> 6], 1);
        }
        __syncthreads();
        for (int i = threadIdx.x; i < NB; i += 256) {
            int c = cnt[i];
            run[i] = c ? (i * CAP + atomicAdd(&gcnt[i], c)) : 0;
        }
        __syncthreads();
        for (int i = b4 + threadIdx.x; i < e4; i += 256) {
            int4 d = ((const int4*)dst)[i];
            int4 s = ((const int4*)src)[i];
            int p0 = atomicAdd(&run[d.x >> 6], 1);
            ebuf[p0] = (unsigned)s.x | ((unsigned)(d.x & 63) << 16);
            int p1 = atomicAdd(&run[d.y >> 6], 1);
            ebuf[p1] = (unsigned)s.y | ((unsigned)(d.y & 63) << 16);
            int p2 = atomicAdd(&run[d.z >> 6], 1);
            ebuf[p2] = (unsigned)s.z | ((unsigned)(d.z & 63) << 16);
            int p3 = atomicAdd(&run[d.w >> 6], 1);
            ebuf[p3] = (unsigned)s.w | ((unsigned)(d.w & 63) << 16);
        }
    } else {
        // ---- layer-0 GEMM: hb0 = bf16(x @ W0^T), 64 rows per block ----
        const int bid = blockIdx.x - SB;
        const int l = threadIdx.x & 63;
        const int w = threadIdx.x >> 6;
        const int r16 = l & 15;
        const int khalf = l >> 4;
        int rowA = bid * 64 + w * 16 + r16;
        if (rowA >= N_NODES) rowA = N_NODES - 1;

        f32x4 acc[8];
#pragma unroll
        for (int ct = 0; ct < 8; ++ct) acc[ct] = (f32x4){0.f, 0.f, 0.f, 0.f};

#pragma unroll
        for (int kt = 0; kt < 4; ++kt) {
            const float* ip = x + (size_t)rowA * 128 + kt * 32 + khalf * 8;
            float4 f0 = ((const float4*)ip)[0];
            float4 f1 = ((const float4*)ip)[1];
            bf16x8 a;
            a[0] = (short)f2bf(f0.x); a[1] = (short)f2bf(f0.y);
            a[2] = (short)f2bf(f0.z); a[3] = (short)f2bf(f0.w);
            a[4] = (short)f2bf(f1.x); a[5] = (short)f2bf(f1.y);
            a[6] = (short)f2bf(f1.z); a[7] = (short)f2bf(f1.w);
#pragma unroll
            for (int ct = 0; ct < 8; ++ct) {
                bf16x8 bfr = *(const bf16x8*)(wb0 + (((ct * 4 + kt) * 64 + l) * 8));
                acc[ct] = __builtin_amdgcn_mfma_f32_16x16x32_bf16(a, bfr, acc[ct], 0, 0, 0);
            }
        }

        const int rowD0 = bid * 64 + w * 16 + khalf * 4;
#pragma unroll
        for (int ct = 0; ct < 8; ++ct) {
            int col = ct * 16 + r16;
#pragma unroll
            for (int rr = 0; rr < 4; ++rr) {
                int row = rowD0 + rr;
                if (row < N_NODES)
                    hb0[(size_t)row * 128 + col] = f2bf(acc[ct][rr]);
            }
        }
    }
}

// per-bucket: compute own start from gcnt prefix (scan fused in), LDS counting
// scatter by dst_low, parallel rank-sort per dst segment, write compacted sorted
// edge list + row_ptr (bit-deterministic).
__global__ __launch_bounds__(256) void bucket_sort(const unsigned* __restrict__ ebuf,
                                                   const int* __restrict__ gcnt,
                                                   unsigned short* __restrict__ edge_src,
                                                   int* __restrict__ row_ptr, int E) {
    int b = blockIdx.x;
    int tid = threadIdx.x;
    __shared__ unsigned raw[CAP];
    __shared__ unsigned grp[CAP];     // segment-grouped full keys (seg<<16 | src)
    __shared__ int bins[64], pref[64], cur[64];
    __shared__ int ws2[4];
    __shared__ int start_sh;

    // ---- fused prefix: start = sum(gcnt[0..b)) ----
    {
        int s = 0;
        for (int i = tid; i < b; i += 256) s += gcnt[i];
        for (int off = 32; off > 0; off >>= 1) s += __shfl_down(s, off);
        int lane = tid & 63, wv = tid >> 6;
        if (lane == 0) ws2[wv] = s;
        __syncthreads();
        if (tid == 0) start_sh = ws2[0] + ws2[1] + ws2[2] + ws2[3];
    }

    int n = gcnt[b]; if (n > CAP) n = CAP;
    const unsigned* slot = ebuf + (size_t)b * CAP;
    for (int i = tid; i < n; i += 256) raw[i] = slot[i];
    if (tid < 64) bins[tid] = 0;
    __syncthreads();
    const int start = start_sh;
    for (int i = tid; i < n; i += 256) atomicAdd(&bins[raw[i] >> 16], 1);
    __syncthreads();
    if (tid < 64) {
        int v = bins[tid];
        int incl = v;
        for (int off = 1; off < 64; off <<= 1) {
            int t = __shfl_up(incl, off);
            if (tid >= off) incl += t;
        }
        pref[tid] = incl - v;
        cur[tid] = incl - v;
    }
    __syncthreads();
    for (int i = tid; i < n; i += 256) {
        unsigned r = raw[i];
        int pos = atomicAdd(&cur[r >> 16], 1);
        grp[pos] = r;
    }
    __syncthreads();
    // parallel rank-sort: independent loads, no serial chain
    for (int i = tid; i < n; i += 256) {
        unsigned v = grp[i];
        int s = v >> 16;
        int lo = pref[s];
        int len = bins[s];
        int rank = 0;
        for (int j = lo; j < lo + len; ++j) {
            unsigned u = grp[j];
            rank += (u < v) || (u == v && j < i);
        }
        edge_src[start + lo + rank] = (unsigned short)(v & 0xffffu);
    }
    int d0 = b * 64;
    if (tid < 64 && d0 + tid < N_NODES) row_ptr[d0 + tid] = start + pref[tid];
    if (b == NB - 1 && tid == 0) row_ptr[N_NODES] = E;
}

// ================= fused gather + GEMM (layers 1,2), 4-deep gather pipeline =================
template <int NCT>
__global__ __launch_bounds__(256) void gather_gemm(const unsigned short* __restrict__ h,
                                                   const int* __restrict__ row_ptr,
                                                   const unsigned short* __restrict__ es,
                                                   const float* __restrict__ bias,
                                                   const short* __restrict__ Wb,
                                                   unsigned short* __restrict__ out, int fout) {
    __shared__ float agg[16][132];
    const int node0 = blockIdx.x * 16;

    {   // ---- gather phase: 16 threads per node, 8 feats each, 4 edges in flight ----
        const int nl = threadIdx.x >> 4;
        const int q  = threadIdx.x & 15;
        const int node = node0 + nl;
        int beg = row_ptr[node], end = row_ptr[node + 1];
        float acc[8];
        float4 c0 = ((const float4*)bias)[q * 2];
        float4 c1 = ((const float4*)bias)[q * 2 + 1];
        acc[0] = c0.x; acc[1] = c0.y; acc[2] = c0.z; acc[3] = c0.w;
        acc[4] = c1.x; acc[5] = c1.y; acc[6] = c1.z; acc[7] = c1.w;
        int e = beg;
        for (; e + 3 < end; e += 4) {
            int s0 = es[e], s1 = es[e + 1], s2 = es[e + 2], s3 = es[e + 3];
            const uint4 v0 = ((const uint4*)(h + (size_t)s0 * 128))[q];
            const uint4 v1 = ((const uint4*)(h + (size_t)s1 * 128))[q];
            const uint4 v2 = ((const uint4*)(h + (size_t)s2 * 128))[q];
            const uint4 v3 = ((const uint4*)(h + (size_t)s3 * 128))[q];
            acc8(acc, v0); acc8(acc, v1); acc8(acc, v2); acc8(acc, v3);
        }
        for (; e < end; ++e) {
            int s = es[e];
            const uint4 v = ((const uint4*)(h + (size_t)s * 128))[q];
            acc8(acc, v);
        }
        float* row = &agg[nl][q * 8];
        ((float4*)row)[0] = make_float4(fmaxf(acc[0], 0.f), fmaxf(acc[1], 0.f),
                                        fmaxf(acc[2], 0.f), fmaxf(acc[3], 0.f));
        ((float4*)row)[1] = make_float4(fmaxf(acc[4], 0.f), fmaxf(acc[5], 0.f),
                                        fmaxf(acc[6], 0.f), fmaxf(acc[7], 0.f));
    }
    __syncthreads();

    // ---- MFMA phase ----
    const int l = threadIdx.x & 63;
    const int w = threadIdx.x >> 6;
    const int r16 = l & 15;
    const int khalf = l >> 4;
    f32x4 acc[(NCT + 3) / 4];
#pragma unroll
    for (int i = 0; i < (NCT + 3) / 4; ++i) acc[i] = (f32x4){0.f, 0.f, 0.f, 0.f};

#pragma unroll
    for (int kt = 0; kt < 4; ++kt) {
        const float* ap = &agg[r16][kt * 32 + khalf * 8];
        float4 f0 = ((const float4*)ap)[0];
        float4 f1 = ((const float4*)ap)[1];
        bf16x8 a;
        a[0] = (short)f2bf(f0.x); a[1] = (short)f2bf(f0.y);
        a[2] = (short)f2bf(f0.z); a[3] = (short)f2bf(f0.w);
        a[4] = (short)f2bf(f1.x); a[5] = (short)f2bf(f1.y);
        a[6] = (short)f2bf(f1.z); a[7] = (short)f2bf(f1.w);
        int i = 0;
#pragma unroll
        for (int ct = w; ct < NCT; ct += 4, ++i) {
            bf16x8 bfr = *(const bf16x8*)(Wb + (((ct * 4 + kt) * 64 + l) * 8));
            acc[i] = __builtin_amdgcn_mfma_f32_16x16x32_bf16(a, bfr, acc[i], 0, 0, 0);
        }
    }

    {
        int i = 0;
#pragma unroll
        for (int ct = w; ct < NCT; ct += 4, ++i) {
            int col = ct * 16 + r16;
            if (col < fout) {
#pragma unroll
                for (int rr = 0; rr < 4; ++rr)
                    out[(size_t)(node0 + khalf * 4 + rr) * fout + col] = f2bf(acc[i][rr]);
            }
        }
    }
}

// ================= final gather (F=40, bf16 in -> f32 out + bias) =================

__global__ void gather_f40_bf(const unsigned short* __restrict__ h,
                              const int* __restrict__ row_ptr,
                              const unsigned short* __restrict__ es,
                              const float* __restrict__ b,
                              float* __restrict__ out) {
    int gid = blockIdx.x * blockDim.x + threadIdx.x;
    int node = gid / 5;
    int q = gid - node * 5;
    if (node >= N_NODES) return;
    int beg = row_ptr[node];
    int end = row_ptr[node + 1];
    float acc[8];
#pragma unroll
    for (int j = 0; j < 8; ++j) acc[j] = b[q * 8 + j];
    int e = beg;
    for (; e + 3 < end; e += 4) {
        int s0 = es[e], s1 = es[e + 1], s2 = es[e + 2], s3 = es[e + 3];
        const uint4 v0 = *(const uint4*)(h + (size_t)s0 * 40 + q * 8);
        const uint4 v1 = *(const uint4*)(h + (size_t)s1 * 40 + q * 8);
        const uint4 v2 = *(const uint4*)(h + (size_t)s2 * 40 + q * 8);
        const uint4 v3 = *(const uint4*)(h + (size_t)s3 * 40 + q * 8);
        acc8(acc, v0); acc8(acc, v1); acc8(acc, v2); acc8(acc, v3);
    }
    for (; e < end; ++e) {
        int s = es[e];
        const uint4 v = *(const uint4*)(h + (size_t)s * 40 + q * 8);
        acc8(acc, v);
    }
    float* o = out + (size_t)node * 40 + q * 8;
    ((float4*)o)[0] = make_float4(acc[0], acc[1], acc[2], acc[3]);
    ((float4*)o)[1] = make_float4(acc[4], acc[5], acc[6], acc[7]);
}

// ================= host =================

extern "C" void kernel_launch(void* const* d_in, const int* in_sizes, int n_in,
                              void* d_out, int out_size, void* d_ws, size_t ws_size,
                              hipStream_t stream) {
    const float* x  = (const float*)d_in[0];
    const int*   ei = (const int*)d_in[1];
    const float* W0 = (const float*)d_in[2];
    const float* b0 = (const float*)d_in[3];
    const float* W1 = (const float*)d_in[4];
    const float* b1 = (const float*)d_in[5];
    const float* W2 = (const float*)d_in[6];
    const float* b2 = (const float*)d_in[7];
    float* out = (float*)d_out;

    const int E = in_sizes[1] / 2;
    const int* src = ei;
    const int* dst = ei + E;

    // workspace layout
    char* p = (char*)d_ws;
    unsigned short* hb0 = (unsigned short*)p;  p += (size_t)N_NODES * 128 * 2;  // L0 out (bf16)
    unsigned short* hb1 = (unsigned short*)p;  p += (size_t)N_NODES * 128 * 2;  // F1 out (bf16)
    unsigned short* hb2 = (unsigned short*)p;  p += (size_t)N_NODES * 40 * 2;   // F2 out (bf16)
    short* wb = (short*)p;                     p += 19 * 2048 * 2;              // wb0|wb1|wb2
    unsigned* ebuf = (unsigned*)p;             p += (size_t)NB * CAP * 4;       // slotted buckets
    int* row_ptr = (int*)p;                    p += (N_NODES + 1) * 4;
    int* gcnt = (int*)p;                       p += NB * 4;
    unsigned short* edge_src = (unsigned short*)p;  // E u16

    short* wb0 = wb;
    short* wb1 = wb + 8 * 2048;
    short* wb2 = wb + 16 * 2048;

    const int SB = (E + PA_CH - 1) / PA_CH;   // scatter blocks (196)
    const int GB = (N_NODES + 63) / 64;       // gemm blocks (782)

    // ---- phase 0: zero gcnt + prep all weights ----
    zero_prep<<<(19 * 2048 + 255) / 256, 256, 0, stream>>>(gcnt, W0, W1, W2, wb);

    // ---- phase 1 (fused): bucket scatter  ||  layer-0 GEMM ----
    fused_phase1<<<SB + GB, 256, 0, stream>>>(src, dst, gcnt, ebuf, E, SB, x, wb0, hb0);

    // ---- CSR finalize (scan fused into sort) ----
    bucket_sort<<<NB, 256, 0, stream>>>(ebuf, gcnt, edge_src, row_ptr, E);

    // ---- layer 1 fused: h1 = bf16(relu(gather(h0)+b0) @ W1^T) ----
    gather_gemm<8><<<N_NODES / 16, 256, 0, stream>>>(hb0, row_ptr, edge_src, b0, wb1, hb1, 128);

    // ---- layer 2 fused: h2 = bf16(relu(gather(h1)+b1) @ W2^T) ----
    gather_gemm<3><<<N_NODES / 16, 256, 0, stream>>>(hb1, row_ptr, edge_src, b1, wb2, hb2, 40);

    // ---- final aggregation: out = gather(h2) + b2 ----
    gather_f40_bf<<<(N_NODES * 5 + 255) / 256, 256, 0, stream>>>(hb2, row_ptr, edge_src, b2, out);
}